// Round 13
// baseline (80.173 us; speedup 1.0000x reference)
//
#include <hip/hip_runtime.h>
#include <math.h>

#define NSIG 1000
#define NP   3997      // interp points = FFT length (odd)
#define KHALF 1999     // distinct spectrum bins: k = 0..1998 (rest mirror)
#define NW   995       // n_windows
#define WIN  20
#define STEPW 4
#define BATCH 4
#define NCH  125       // window chunks per batch row (8 windows each)
#define CW   8         // windows per chunk

// ws layout (bytes):
//   ks   : [0, 65536)        BATCH*NP floats; pad is read-only garbage
//   tw   : [65536, 97512)    NP float2
//   S    : [98304, 226208)   BATCH*NP float2 (first KHALF per row used)
//   rmax : [226304, 226320)  BATCH uint
//   cmax : [226432, 228432)  BATCH*NCH floats
//   wcut : [229376, 245296)  BATCH*NW floats

__device__ __forceinline__ double interp_at(const float* __restrict__ s, int p) {
    int i0 = p >> 2;
    int si = p & 3;
    double ss = 0.25 * (double)si;
    const double A = -0.75;
    double d0 = ss + 1.0;
    double w0 = ((A * d0 - 5.0 * A) * d0 + 8.0 * A) * d0 - 4.0 * A;
    double w1 = ((A + 2.0) * ss - (A + 3.0)) * ss * ss + 1.0;
    double d2 = 1.0 - ss;
    double w2 = ((A + 2.0) * d2 - (A + 3.0)) * d2 * d2 + 1.0;
    double d3 = 2.0 - ss;
    double w3 = ((A * d3 - 5.0 * A) * d3 + 8.0 * A) * d3 - 4.0 * A;
    int im1 = i0 - 1; if (im1 < 0) im1 = 0;
    int ip1 = i0 + 1; if (ip1 > NSIG - 1) ip1 = NSIG - 1;
    int ip2 = i0 + 2; if (ip2 > NSIG - 1) ip2 = NSIG - 1;
    return w0 * (double)s[im1] + w1 * (double)s[i0] +
           w2 * (double)s[ip1] + w3 * (double)s[ip2];
}

// K1: fused init + full DFT (identical to R12).
__global__ __launch_bounds__(512) void dft_init_kernel(
        const float* __restrict__ sig, const float* __restrict__ gamma_raw,
        float* __restrict__ ks, float2* __restrict__ tw, float2* __restrict__ S,
        unsigned int* __restrict__ rmax) {
    __shared__ float   lks[NP];
    __shared__ double2 redd[512];
    int b = blockIdx.y;
    int bx = blockIdx.x;
    int tid = threadIdx.x;
    const float* srow = sig + b * NSIG;

    double lmin = 1e300;
    #pragma unroll
    for (int i = 0; i < 8; ++i) {
        int p = tid + i * 512;
        if (p < NP) lmin = fmin(lmin, interp_at(srow, p));
    }
    redd[tid].x = lmin;
    __syncthreads();
    for (int s = 256; s > 0; s >>= 1) {
        if (tid < s) redd[tid].x = fmin(redd[tid].x, redd[tid + s].x);
        __syncthreads();
    }
    double m = fmin(redd[0].x, 0.0);
    double g0r = (double)gamma_raw[0], g1r = (double)gamma_raw[1];
    double mx = fmax(g0r, g1r);
    double e0 = exp(g0r - mx), e1 = exp(g1r - mx);
    double inv = 1.0 / (e0 + e1);
    double g0 = e0 * inv, g1 = e1 * inv;
    #pragma unroll
    for (int i = 0; i < 8; ++i) {
        int p = tid + i * 512;
        if (p < NP) {
            double x = interp_at(srow, p) - m;
            double poly = (x + 1.3) * (x + 1.3);
            double gauss = exp(-0.5 * (x - 0.7) * (x - 0.7));
            float v = (float)(g0 * poly + g1 * gauss);
            lks[p] = v;
            if (bx == 0) ks[b * NP + p] = v;
        }
    }
    if (b == 0 && bx < 8) {
        int mm = bx * 512 + tid;
        if (mm < NP) {
            double ang = -6.283185307179586476925286766559 * ((double)mm / (double)NP);
            double sv, cv; sincos(ang, &sv, &cv);
            tw[mm] = make_float2((float)cv, (float)sv);
        }
        if (bx == 0 && tid < BATCH) rmax[tid] = 0u;
    }
    __syncthreads();

    int kk = tid & 15, tc = tid >> 4;
    int k = bx * 16 + kk;
    double sr = 0.0, si = 0.0;
    if (k < KHALF) {
        int t0 = tc * 125;
        int t1 = t0 + 125; if (t1 > NP) t1 = NP;
        const double TWO_PI = 6.283185307179586476925286766559;
        double base = -TWO_PI / (double)NP;
        double rr, ri;
        sincos(base * (double)k, &ri, &rr);
        int m0 = (k * t0) % NP;
        double pr, pi;
        sincos(base * (double)m0, &pi, &pr);
        for (int t = t0; t < t1; ++t) {
            double kv = (double)lks[t];
            sr = fma(kv, pr, sr);
            si = fma(kv, pi, si);
            double nr = pr * rr - pi * ri;
            double ni = pr * ri + pi * rr;
            pr = nr; pi = ni;
        }
    }
    redd[tid] = make_double2(sr, si);
    __syncthreads();
    for (int s = 256; s >= 16; s >>= 1) {
        if (tid < s) {
            redd[tid].x += redd[tid + s].x;
            redd[tid].y += redd[tid + s].y;
        }
        __syncthreads();
    }
    if (tid < 16) {
        int kw = bx * 16 + tid;
        if (kw < KHALF)
            S[b * NP + kw] = make_float2((float)redd[tid].x, (float)redd[tid].y);
    }
}

__device__ __forceinline__ float wavemax(float x) {
    #pragma unroll
    for (int off = 32; off > 0; off >>= 1)
        x = fmaxf(x, __shfl_xor(x, off));
    return x;
}

// sliding step bin n: W += (cn*r20 - co) * q ; q *= r
#define SLIDE1(n, co, cn) { \
    float ax = fmaf((cn), T##n.x, -(co)); \
    float ay = (cn) * T##n.y; \
    Wx##n = fmaf(ax, Q##n.x, fmaf(-ay, Q##n.y, Wx##n)); \
    Wy##n = fmaf(ax, Q##n.y, fmaf(ay, Q##n.x, Wy##n)); \
    float tq = fmaf(Q##n.x, R##n.x, -(Q##n.y * R##n.y)); \
    Q##n.y = fmaf(Q##n.x, R##n.y, Q##n.y * R##n.x); \
    Q##n.x = tq; }

#define SLIDEJ(co, cn) SLIDE1(0, co, cn) SLIDE1(1, co, cn) SLIDE1(2, co, cn) SLIDE1(3, co, cn)

#define SLIDE4(base) { \
    { float co = kp[(base) + 0], cn = kp[(base) + 20]; SLIDEJ(co, cn) } \
    { float co = kp[(base) + 1], cn = kp[(base) + 21]; SLIDEJ(co, cn) } \
    { float co = kp[(base) + 2], cn = kp[(base) + 22]; SLIDEJ(co, cn) } \
    { float co = kp[(base) + 3], cn = kp[(base) + 23]; SLIDEJ(co, cn) } }

#define WINBODY(w) { \
    float M0 = sqrtf(fmaf(Wx0, Wx0, Wy0 * Wy0)); \
    float M1m = sqrtf(fmaf(Wx1, Wx1, Wy1 * Wy1)); \
    float M2m = sqrtf(fmaf(Wx2, Wx2, Wy2 * Wy2)); \
    float M3m = sqrtf(fmaf(Wx3, Wx3, Wy3 * Wy3)); \
    float lm = fmaxf(fmaxf(M0, M1m), fmaxf(M2m, v3 ? M3m : 0.f)); \
    lm = wavemax(lm); \
    if ((tid & 63) == 0) wred[tid >> 6] = lm; \
    __syncthreads(); \
    float bm = fmaxf(fmaxf(fmaxf(wred[0], wred[1]), fmaxf(wred[2], wred[3])), \
                     fmaxf(fmaxf(wred[4], wred[5]), fmaxf(wred[6], wred[7]))); \
    float cut = bm * alpha; \
    __syncthreads(); \
    if (w0 + (w) < NW) { \
        if (tid == 0) wcut[b * NW + w0 + (w)] = cut; \
        float r0v = 0.f, r1v = 0.f, r2v = 0.f, r3v = 0.f; \
        { float dr = Sv0.x - Wx0, di = Sv0.y - Wy0; float m1 = sqrtf(fmaf(dr, dr, di * di)); \
          if (M0 > cut) r0v = fminf(M0, m1 * M0); } \
        { float dr = Sv1.x - Wx1, di = Sv1.y - Wy1; float m1 = sqrtf(fmaf(dr, dr, di * di)); \
          if (M1m > cut) r1v = fminf(M1m, m1 * M1m); } \
        { float dr = Sv2.x - Wx2, di = Sv2.y - Wy2; float m1 = sqrtf(fmaf(dr, dr, di * di)); \
          if (M2m > cut) r2v = fminf(M2m, m1 * M2m); } \
        { float dr = Sv3.x - Wx3, di = Sv3.y - Wy3; float m1 = sqrtf(fmaf(dr, dr, di * di)); \
          if (M3m > cut) r3v = fminf(M3m, m1 * M3m); } \
        rl = fmaxf(rl, fmaxf(fmaxf(r0v, r1v), fmaxf(r2v, r3v))); \
    } }

// K2: chunk of 8 windows. FIRST: fire-and-forget float4 zero of this chunk's
// contiguous out stripe (~128KB) — HBM drain overlaps the slide compute below.
// THEN: sliding spectrum -> wcut/cmax/rmax (no other out writes).
__global__ __launch_bounds__(512, 4) void window_kernel(
        const float* __restrict__ ks, const float2* __restrict__ tw,
        const float2* __restrict__ S, const float* __restrict__ alpha_p,
        float* __restrict__ wcut, float* __restrict__ cmax,
        unsigned int* __restrict__ rmax, float* __restrict__ out) {
    __shared__ float wred[8];
    int b = blockIdx.y;
    int wc = blockIdx.x;
    int w0 = wc * CW;
    int s0 = w0 * STEPW;
    int tid = threadIdx.x;

    // ---- zero this chunk's rows (contiguous stripe), issued up-front ----
    {
        size_t zbase = (size_t)(b * NW + w0) * NP;
        int nrows = NW - w0; if (nrows > CW) nrows = CW;
        size_t nflt = (size_t)nrows * NP;
        int h = (4 - (int)(zbase & 3)) & 3;
        size_t nv = (nflt - h) >> 2;
        size_t t0 = h + (nv << 2);
        float4* vp = (float4*)(out + zbase + h);
        float4 z4 = make_float4(0.f, 0.f, 0.f, 0.f);
        for (size_t v = tid; v < nv; v += 512) vp[v] = z4;
        if (tid < h) out[zbase + tid] = 0.f;
        if ((size_t)tid < nflt - t0) out[zbase + t0 + tid] = 0.f;
    }

    float alpha = *alpha_p;
    const float* kp = ks + b * NP + s0;   // block-uniform -> s_load taps

    int k0 = tid, k1 = tid + 512, k2 = tid + 1024, k3 = tid + 1536;
    bool v3 = (k3 < KHALF);

    float2 R0 = tw[k0], R1 = tw[k1], R2 = tw[k2], R3 = tw[k3];
    float2 T0 = tw[(20 * k0) % NP], T1 = tw[(20 * k1) % NP],
           T2 = tw[(20 * k2) % NP], T3 = tw[(20 * k3) % NP];
    float2 Q0 = tw[(k0 * s0) % NP], Q1 = tw[(k1 * s0) % NP],
           Q2 = tw[(k2 * s0) % NP], Q3 = tw[(k3 * s0) % NP];
    const float2* Sb = S + b * NP;
    float2 Sv0 = Sb[k0], Sv1 = Sb[k1], Sv2 = Sb[k2], Sv3 = Sb[k3];

    float Dx0 = kp[19], Dy0 = 0.f, Dx1 = kp[19], Dy1 = 0.f,
          Dx2 = kp[19], Dy2 = 0.f, Dx3 = kp[19], Dy3 = 0.f;
    #pragma unroll
    for (int j = 18; j >= 0; --j) {
        float a = kp[j];
        float nx, ny;
        nx = fmaf(Dx0, R0.x, fmaf(-Dy0, R0.y, a));
        ny = fmaf(Dy0, R0.x, Dx0 * R0.y);
        Dx0 = nx; Dy0 = ny;
        nx = fmaf(Dx1, R1.x, fmaf(-Dy1, R1.y, a));
        ny = fmaf(Dy1, R1.x, Dx1 * R1.y);
        Dx1 = nx; Dy1 = ny;
        nx = fmaf(Dx2, R2.x, fmaf(-Dy2, R2.y, a));
        ny = fmaf(Dy2, R2.x, Dx2 * R2.y);
        Dx2 = nx; Dy2 = ny;
        nx = fmaf(Dx3, R3.x, fmaf(-Dy3, R3.y, a));
        ny = fmaf(Dy3, R3.x, Dx3 * R3.y);
        Dx3 = nx; Dy3 = ny;
    }
    float Wx0 = fmaf(Q0.x, Dx0, -(Q0.y * Dy0));
    float Wy0 = fmaf(Q0.x, Dy0, Q0.y * Dx0);
    float Wx1 = fmaf(Q1.x, Dx1, -(Q1.y * Dy1));
    float Wy1 = fmaf(Q1.x, Dy1, Q1.y * Dx1);
    float Wx2 = fmaf(Q2.x, Dx2, -(Q2.y * Dy2));
    float Wy2 = fmaf(Q2.x, Dy2, Q2.y * Dx2);
    float Wx3 = fmaf(Q3.x, Dx3, -(Q3.y * Dy3));
    float Wy3 = fmaf(Q3.x, Dy3, Q3.y * Dx3);

    float rl = 0.f;

    WINBODY(0)
    SLIDE4(0)  WINBODY(1)
    SLIDE4(4)  WINBODY(2)
    SLIDE4(8)  WINBODY(3)
    SLIDE4(12) WINBODY(4)
    SLIDE4(16) WINBODY(5)
    SLIDE4(20) WINBODY(6)
    SLIDE4(24) WINBODY(7)

    rl = wavemax(rl);
    if ((tid & 63) == 0) wred[tid >> 6] = rl;
    __syncthreads();
    if (tid == 0) {
        float bm = fmaxf(fmaxf(fmaxf(wred[0], wred[1]), fmaxf(wred[2], wred[3])),
                         fmaxf(fmaxf(wred[4], wred[5]), fmaxf(wred[6], wred[7])));
        cmax[b * NCH + wc] = bm;
        atomicMax(&rmax[b], __float_as_uint(bm));
    }
}

// survivor bin epilogue (out rows already zeroed by window_kernel)
#define FINBIN(n, kn, valid) { \
    if (valid) { \
        float M = sqrtf(fmaf(Dx##n, Dx##n, Dy##n * Dy##n)); \
        float2 P = tw[((kn) * start) % NP]; \
        float Wr = fmaf(P.x, Dx##n, -(P.y * Dy##n)); \
        float Wi = fmaf(P.x, Dy##n, P.y * Dx##n); \
        float2 Sv = Sb[kn]; \
        float dr = Sv.x - Wr, di = Sv.y - Wi; \
        float M1 = sqrtf(fmaf(dr, dr, di * di)); \
        float res = 0.f; \
        if (M > cut) res = fminf(M, M1 * M); \
        float f = (res > thr) ? res : 0.f; \
        out[base + (kn)] = f; \
        if ((kn) > 0) out[base + NP - (kn)] = f; \
    } }

// K3: sparse finalize. One block per chunk; dead chunks (almost all) return
// after two scalar loads. Survivors recompute their 8 rows by Horner and
// overwrite the pre-zeroed rows with full mirrored values.
__global__ __launch_bounds__(512) void sparse_kernel(
        const float* __restrict__ ks, const float2* __restrict__ tw,
        const float2* __restrict__ S, const float* __restrict__ wcut,
        const float* __restrict__ cmax, const unsigned int* __restrict__ rmax,
        const float* __restrict__ beta_p, float* __restrict__ out) {
    int b = blockIdx.y, wc = blockIdx.x;
    float thr = (*beta_p) * __uint_as_float(rmax[b]);
    if (cmax[b * NCH + wc] <= thr) return;

    int tid = threadIdx.x;
    int k0 = tid, k1 = tid + 512, k2 = tid + 1024, k3 = tid + 1536;
    bool v3 = (k3 < KHALF);
    float2 R0 = tw[k0], R1 = tw[k1], R2 = tw[k2], R3 = tw[k3];
    const float2* Sb = S + b * NP;

    for (int i = 0; i < CW; ++i) {
        int w = wc * CW + i;
        if (w >= NW) break;
        int start = w * STEPW;
        const float* kp = ks + b * NP + start;
        float cut = wcut[b * NW + w];
        size_t base = (size_t)(b * NW + w) * NP;
        float Dx0 = kp[19], Dy0 = 0.f, Dx1 = kp[19], Dy1 = 0.f,
              Dx2 = kp[19], Dy2 = 0.f, Dx3 = kp[19], Dy3 = 0.f;
        #pragma unroll
        for (int j = 18; j >= 0; --j) {
            float a = kp[j];
            float nx, ny;
            nx = fmaf(Dx0, R0.x, fmaf(-Dy0, R0.y, a));
            ny = fmaf(Dy0, R0.x, Dx0 * R0.y);
            Dx0 = nx; Dy0 = ny;
            nx = fmaf(Dx1, R1.x, fmaf(-Dy1, R1.y, a));
            ny = fmaf(Dy1, R1.x, Dx1 * R1.y);
            Dx1 = nx; Dy1 = ny;
            nx = fmaf(Dx2, R2.x, fmaf(-Dy2, R2.y, a));
            ny = fmaf(Dy2, R2.x, Dx2 * R2.y);
            Dx2 = nx; Dy2 = ny;
            nx = fmaf(Dx3, R3.x, fmaf(-Dy3, R3.y, a));
            ny = fmaf(Dy3, R3.x, Dx3 * R3.y);
            Dx3 = nx; Dy3 = ny;
        }
        FINBIN(0, k0, true)
        FINBIN(1, k1, true)
        FINBIN(2, k2, true)
        FINBIN(3, k3, v3)
    }
}

extern "C" void kernel_launch(void* const* d_in, const int* in_sizes, int n_in,
                              void* d_out, int out_size, void* d_ws, size_t ws_size,
                              hipStream_t stream) {
    const float* sig       = (const float*)d_in[0];
    const float* alpha_p   = (const float*)d_in[1];
    const float* beta_p    = (const float*)d_in[2];
    const float* gamma_raw = (const float*)d_in[3];
    char* ws = (char*)d_ws;
    float*        ks   = (float*)(ws + 0);
    float2*       tw   = (float2*)(ws + 65536);
    float2*       S    = (float2*)(ws + 98304);
    unsigned int* rmax = (unsigned int*)(ws + 226304);
    float*        cmax = (float*)(ws + 226432);
    float*        wcut = (float*)(ws + 229376);
    float* out = (float*)d_out;

    hipLaunchKernelGGL(dft_init_kernel, dim3(125, BATCH), dim3(512), 0, stream,
                       sig, gamma_raw, ks, tw, S, rmax);
    hipLaunchKernelGGL(window_kernel,   dim3(NCH, BATCH), dim3(512), 0, stream,
                       ks, tw, S, alpha_p, wcut, cmax, rmax, out);
    hipLaunchKernelGGL(sparse_kernel,   dim3(NCH, BATCH), dim3(512), 0, stream,
                       ks, tw, S, wcut, cmax, rmax, beta_p, out);
}

// Round 14
// 58.115 us; speedup vs baseline: 1.3795x; 1.3795x over previous
//
#include <hip/hip_runtime.h>
#include <math.h>

#define NSIG 1000
#define NP   3997      // interp points = FFT length (odd)
#define KHALF 1999     // distinct spectrum bins: k = 0..1998 (rest mirror)
#define NW   995       // n_windows
#define WIN  20
#define STEPW 4
#define BATCH 4
#define NCH  125       // window chunks per batch row (8 windows each)
#define CW   8         // windows per chunk

// ws layout (bytes):
//   ks   : [0, 65536)        BATCH*NP floats; pad is read-only garbage
//   tw   : [65536, 97512)    NP float2
//   S    : [98304, 226208)   BATCH*NP float2 (first KHALF per row used)
//   rmax : [226304, 226320)  BATCH uint
//   cmax : [226432, 228432)  BATCH*NCH floats
//   wcut : [229376, 245296)  BATCH*NW floats

__device__ __forceinline__ double interp_at(const float* __restrict__ s, int p) {
    int i0 = p >> 2;
    int si = p & 3;
    double ss = 0.25 * (double)si;
    const double A = -0.75;
    double d0 = ss + 1.0;
    double w0 = ((A * d0 - 5.0 * A) * d0 + 8.0 * A) * d0 - 4.0 * A;
    double w1 = ((A + 2.0) * ss - (A + 3.0)) * ss * ss + 1.0;
    double d2 = 1.0 - ss;
    double w2 = ((A + 2.0) * d2 - (A + 3.0)) * d2 * d2 + 1.0;
    double d3 = 2.0 - ss;
    double w3 = ((A * d3 - 5.0 * A) * d3 + 8.0 * A) * d3 - 4.0 * A;
    int im1 = i0 - 1; if (im1 < 0) im1 = 0;
    int ip1 = i0 + 1; if (ip1 > NSIG - 1) ip1 = NSIG - 1;
    int ip2 = i0 + 2; if (ip2 > NSIG - 1) ip2 = NSIG - 1;
    return w0 * (double)s[im1] + w1 * (double)s[i0] +
           w2 * (double)s[ip1] + w3 * (double)s[ip2];
}

// K1: fused init + full DFT. Step-rotation sincos computed once per bin
// (16 per block) and shared via LDS instead of once per thread.
__global__ __launch_bounds__(512) void dft_init_kernel(
        const float* __restrict__ sig, const float* __restrict__ gamma_raw,
        float* __restrict__ ks, float2* __restrict__ tw, float2* __restrict__ S,
        unsigned int* __restrict__ rmax) {
    __shared__ float   lks[NP];
    __shared__ double2 redd[512];
    __shared__ double  rrs[16], ris[16];
    int b = blockIdx.y;
    int bx = blockIdx.x;
    int tid = threadIdx.x;
    const float* srow = sig + b * NSIG;
    const double TWO_PI = 6.283185307179586476925286766559;
    const double abase = -TWO_PI / (double)NP;

    double lmin = 1e300;
    #pragma unroll
    for (int i = 0; i < 8; ++i) {
        int p = tid + i * 512;
        if (p < NP) lmin = fmin(lmin, interp_at(srow, p));
    }
    redd[tid].x = lmin;
    __syncthreads();
    for (int s = 256; s > 0; s >>= 1) {
        if (tid < s) redd[tid].x = fmin(redd[tid].x, redd[tid + s].x);
        __syncthreads();
    }
    double m = fmin(redd[0].x, 0.0);
    double g0r = (double)gamma_raw[0], g1r = (double)gamma_raw[1];
    double mx = fmax(g0r, g1r);
    double e0 = exp(g0r - mx), e1 = exp(g1r - mx);
    double inv = 1.0 / (e0 + e1);
    double g0 = e0 * inv, g1 = e1 * inv;
    #pragma unroll
    for (int i = 0; i < 8; ++i) {
        int p = tid + i * 512;
        if (p < NP) {
            double x = interp_at(srow, p) - m;
            double poly = (x + 1.3) * (x + 1.3);
            double gauss = exp(-0.5 * (x - 0.7) * (x - 0.7));
            float v = (float)(g0 * poly + g1 * gauss);
            lks[p] = v;
            if (bx == 0) ks[b * NP + p] = v;
        }
    }
    if (b == 0 && bx < 8) {
        int mm = bx * 512 + tid;
        if (mm < NP) {
            double ang = abase * (double)mm;
            double sv, cv; sincos(ang, &sv, &cv);
            tw[mm] = make_float2((float)cv, (float)sv);
        }
        if (bx == 0 && tid < BATCH) rmax[tid] = 0u;
    }
    // shared step rotation for this block's 16 bins
    if (tid < 16) {
        double sv, cv;
        sincos(abase * (double)(bx * 16 + tid), &sv, &cv);
        rrs[tid] = cv; ris[tid] = sv;
    }
    __syncthreads();

    int kk = tid & 15, tc = tid >> 4;
    int k = bx * 16 + kk;
    double sr = 0.0, si = 0.0;
    if (k < KHALF) {
        int t0 = tc * 125;
        int t1 = t0 + 125; if (t1 > NP) t1 = NP;
        double rr = rrs[kk], ri = ris[kk];
        int m0 = (k * t0) % NP;
        double pr, pi;
        sincos(abase * (double)m0, &pi, &pr);
        for (int t = t0; t < t1; ++t) {
            double kv = (double)lks[t];
            sr = fma(kv, pr, sr);
            si = fma(kv, pi, si);
            double nr = pr * rr - pi * ri;
            double ni = pr * ri + pi * rr;
            pr = nr; pi = ni;
        }
    }
    redd[tid] = make_double2(sr, si);
    __syncthreads();
    for (int s = 256; s >= 16; s >>= 1) {
        if (tid < s) {
            redd[tid].x += redd[tid + s].x;
            redd[tid].y += redd[tid + s].y;
        }
        __syncthreads();
    }
    if (tid < 16) {
        int kw = bx * 16 + tid;
        if (kw < KHALF)
            S[b * NP + kw] = make_float2((float)redd[tid].x, (float)redd[tid].y);
    }
}

__device__ __forceinline__ float wavemax(float x) {
    #pragma unroll
    for (int off = 32; off > 0; off >>= 1)
        x = fmaxf(x, __shfl_xor(x, off));
    return x;
}

// sliding step bin n: W += (cn*r20 - co) * q ; q *= r
#define SLIDE1(n, co, cn) { \
    float ax = fmaf((cn), T##n.x, -(co)); \
    float ay = (cn) * T##n.y; \
    Wx##n = fmaf(ax, Q##n.x, fmaf(-ay, Q##n.y, Wx##n)); \
    Wy##n = fmaf(ax, Q##n.y, fmaf(ay, Q##n.x, Wy##n)); \
    float tq = fmaf(Q##n.x, R##n.x, -(Q##n.y * R##n.y)); \
    Q##n.y = fmaf(Q##n.x, R##n.y, Q##n.y * R##n.x); \
    Q##n.x = tq; }

#define SLIDEJ(co, cn) SLIDE1(0, co, cn) SLIDE1(1, co, cn) SLIDE1(2, co, cn) SLIDE1(3, co, cn)

#define SLIDE4(base) { \
    { float co = kp[(base) + 0], cn = kp[(base) + 20]; SLIDEJ(co, cn) } \
    { float co = kp[(base) + 1], cn = kp[(base) + 21]; SLIDEJ(co, cn) } \
    { float co = kp[(base) + 2], cn = kp[(base) + 22]; SLIDEJ(co, cn) } \
    { float co = kp[(base) + 3], cn = kp[(base) + 23]; SLIDEJ(co, cn) } }

#define SNAP() { Ax0=Wx0;Ay0=Wy0;Ax1=Wx1;Ay1=Wy1;Ax2=Wx2;Ay2=Wy2;Ax3=Wx3;Ay3=Wy3; }

#define MAX8(a) fmaxf(fmaxf(fmaxf((a)[0],(a)[1]),fmaxf((a)[2],(a)[3])), \
                      fmaxf(fmaxf((a)[4],(a)[5]),fmaxf((a)[6],(a)[7])))

// pair body: A holds window wa, W holds window wa+1; one barrier for both cuts
#define PB(wa, bf) { \
    float MA0 = sqrtf(fmaf(Ax0,Ax0,Ay0*Ay0)); \
    float MA1 = sqrtf(fmaf(Ax1,Ax1,Ay1*Ay1)); \
    float MA2 = sqrtf(fmaf(Ax2,Ax2,Ay2*Ay2)); \
    float MA3 = sqrtf(fmaf(Ax3,Ax3,Ay3*Ay3)); \
    float MB0 = sqrtf(fmaf(Wx0,Wx0,Wy0*Wy0)); \
    float MB1 = sqrtf(fmaf(Wx1,Wx1,Wy1*Wy1)); \
    float MB2 = sqrtf(fmaf(Wx2,Wx2,Wy2*Wy2)); \
    float MB3 = sqrtf(fmaf(Wx3,Wx3,Wy3*Wy3)); \
    float lmA = fmaxf(fmaxf(MA0, MA1), fmaxf(MA2, v3 ? MA3 : 0.f)); \
    float lmB = fmaxf(fmaxf(MB0, MB1), fmaxf(MB2, v3 ? MB3 : 0.f)); \
    lmA = wavemax(lmA); \
    lmB = wavemax(lmB); \
    if ((tid & 63) == 0) { wrA[bf][wv] = lmA; wrB[bf][wv] = lmB; } \
    __syncthreads(); \
    float cutA = alpha * MAX8(wrA[bf]); \
    float cutB = alpha * MAX8(wrB[bf]); \
    if (w0 + (wa) < NW) { \
        if (tid == 0) wcut[b * NW + w0 + (wa)] = cutA; \
        float r0=0.f,r1=0.f,r2=0.f,r3=0.f; \
        { float dr=Sv0.x-Ax0, di=Sv0.y-Ay0; float m1=sqrtf(fmaf(dr,dr,di*di)); if (MA0>cutA) r0=fminf(MA0,m1*MA0); } \
        { float dr=Sv1.x-Ax1, di=Sv1.y-Ay1; float m1=sqrtf(fmaf(dr,dr,di*di)); if (MA1>cutA) r1=fminf(MA1,m1*MA1); } \
        { float dr=Sv2.x-Ax2, di=Sv2.y-Ay2; float m1=sqrtf(fmaf(dr,dr,di*di)); if (MA2>cutA) r2=fminf(MA2,m1*MA2); } \
        if (v3) { float dr=Sv3.x-Ax3, di=Sv3.y-Ay3; float m1=sqrtf(fmaf(dr,dr,di*di)); if (MA3>cutA) r3=fminf(MA3,m1*MA3); } \
        rl = fmaxf(rl, fmaxf(fmaxf(r0,r1),fmaxf(r2,r3))); \
    } \
    if (w0 + (wa) + 1 < NW) { \
        if (tid == 0) wcut[b * NW + w0 + (wa) + 1] = cutB; \
        float r0=0.f,r1=0.f,r2=0.f,r3=0.f; \
        { float dr=Sv0.x-Wx0, di=Sv0.y-Wy0; float m1=sqrtf(fmaf(dr,dr,di*di)); if (MB0>cutB) r0=fminf(MB0,m1*MB0); } \
        { float dr=Sv1.x-Wx1, di=Sv1.y-Wy1; float m1=sqrtf(fmaf(dr,dr,di*di)); if (MB1>cutB) r1=fminf(MB1,m1*MB1); } \
        { float dr=Sv2.x-Wx2, di=Sv2.y-Wy2; float m1=sqrtf(fmaf(dr,dr,di*di)); if (MB2>cutB) r2=fminf(MB2,m1*MB2); } \
        if (v3) { float dr=Sv3.x-Wx3, di=Sv3.y-Wy3; float m1=sqrtf(fmaf(dr,dr,di*di)); if (MB3>cutB) r3=fminf(MB3,m1*MB3); } \
        rl = fmaxf(rl, fmaxf(fmaxf(r0,r1),fmaxf(r2,r3))); \
    } }

// K2: chunk of 8 windows; sliding spectrum; pairwise reduction (5 barriers);
// only wcut/cmax/rmax stores.
__global__ __launch_bounds__(512, 4) void window_kernel(
        const float* __restrict__ ks, const float2* __restrict__ tw,
        const float2* __restrict__ S, const float* __restrict__ alpha_p,
        float* __restrict__ wcut, float* __restrict__ cmax,
        unsigned int* __restrict__ rmax) {
    __shared__ float wrA[2][8], wrB[2][8];
    int b = blockIdx.y;
    int wc = blockIdx.x;
    int w0 = wc * CW;
    int s0 = w0 * STEPW;
    int tid = threadIdx.x;
    int wv = tid >> 6;
    float alpha = *alpha_p;
    const float* kp = ks + b * NP + s0;   // block-uniform -> s_load taps

    int k0 = tid, k1 = tid + 512, k2 = tid + 1024, k3 = tid + 1536;
    bool v3 = (k3 < KHALF);

    float2 R0 = tw[k0], R1 = tw[k1], R2 = tw[k2], R3 = tw[k3];
    float2 T0 = tw[(20 * k0) % NP], T1 = tw[(20 * k1) % NP],
           T2 = tw[(20 * k2) % NP], T3 = tw[(20 * k3) % NP];
    float2 Q0 = tw[(k0 * s0) % NP], Q1 = tw[(k1 * s0) % NP],
           Q2 = tw[(k2 * s0) % NP], Q3 = tw[(k3 * s0) % NP];
    const float2* Sb = S + b * NP;
    float2 Sv0 = Sb[k0], Sv1 = Sb[k1], Sv2 = Sb[k2], Sv3 = Sb[k3];

    // Horner for window 0: D = sum_j kp[j] r^j
    float Dx0 = kp[19], Dy0 = 0.f, Dx1 = kp[19], Dy1 = 0.f,
          Dx2 = kp[19], Dy2 = 0.f, Dx3 = kp[19], Dy3 = 0.f;
    #pragma unroll
    for (int j = 18; j >= 0; --j) {
        float a = kp[j];
        float nx, ny;
        nx = fmaf(Dx0, R0.x, fmaf(-Dy0, R0.y, a));
        ny = fmaf(Dy0, R0.x, Dx0 * R0.y);
        Dx0 = nx; Dy0 = ny;
        nx = fmaf(Dx1, R1.x, fmaf(-Dy1, R1.y, a));
        ny = fmaf(Dy1, R1.x, Dx1 * R1.y);
        Dx1 = nx; Dy1 = ny;
        nx = fmaf(Dx2, R2.x, fmaf(-Dy2, R2.y, a));
        ny = fmaf(Dy2, R2.x, Dx2 * R2.y);
        Dx2 = nx; Dy2 = ny;
        nx = fmaf(Dx3, R3.x, fmaf(-Dy3, R3.y, a));
        ny = fmaf(Dy3, R3.x, Dx3 * R3.y);
        Dx3 = nx; Dy3 = ny;
    }
    // absolute-phase spectrum of window 0: W = Q * D
    float Wx0 = fmaf(Q0.x, Dx0, -(Q0.y * Dy0));
    float Wy0 = fmaf(Q0.x, Dy0, Q0.y * Dx0);
    float Wx1 = fmaf(Q1.x, Dx1, -(Q1.y * Dy1));
    float Wy1 = fmaf(Q1.x, Dy1, Q1.y * Dx1);
    float Wx2 = fmaf(Q2.x, Dx2, -(Q2.y * Dy2));
    float Wy2 = fmaf(Q2.x, Dy2, Q2.y * Dx2);
    float Wx3 = fmaf(Q3.x, Dx3, -(Q3.y * Dy3));
    float Wy3 = fmaf(Q3.x, Dy3, Q3.y * Dx3);

    float Ax0, Ay0, Ax1, Ay1, Ax2, Ay2, Ax3, Ay3;
    float rl = 0.f;

    SNAP() SLIDE4(0)                    PB(0, 0)
    SLIDE4(4)  SNAP() SLIDE4(8)        PB(2, 1)
    SLIDE4(12) SNAP() SLIDE4(16)       PB(4, 0)
    SLIDE4(20) SNAP() SLIDE4(24)       PB(6, 1)

    rl = wavemax(rl);
    if ((tid & 63) == 0) wrA[0][wv] = rl;
    __syncthreads();
    if (tid == 0) {
        float bm = MAX8(wrA[0]);
        cmax[b * NCH + wc] = bm;
        atomicMax(&rmax[b], __float_as_uint(bm));
    }
}

// finalize survivor bin epilogue
#define FINBIN(n, kn, valid) { \
    if (valid) { \
        float M = sqrtf(fmaf(Dx##n, Dx##n, Dy##n * Dy##n)); \
        float2 P = tw[((kn) * start) % NP]; \
        float Wr = fmaf(P.x, Dx##n, -(P.y * Dy##n)); \
        float Wi = fmaf(P.x, Dy##n, P.y * Dx##n); \
        float2 Sv = Sb[kn]; \
        float dr = Sv.x - Wr, di = Sv.y - Wi; \
        float M1 = sqrtf(fmaf(dr, dr, di * di)); \
        float res = 0.f; \
        if (M > cut) res = fminf(M, M1 * M); \
        float f = (res > thr) ? res : 0.f; \
        out[base + (kn)] = f; \
        if ((kn) > 0) out[base + NP - (kn)] = f; \
    } }

// K3: one block per (b,w) row (R12). Dead chunks -> float4 zero row.
// Survivors -> Horner recompute + mirrored write.
__global__ __launch_bounds__(512) void finalize_kernel(
        const float* __restrict__ ks, const float2* __restrict__ tw,
        const float2* __restrict__ S, const float* __restrict__ wcut,
        const float* __restrict__ cmax, const unsigned int* __restrict__ rmax,
        const float* __restrict__ beta_p, float* __restrict__ out) {
    int b = blockIdx.y, w = blockIdx.x;
    int tid = threadIdx.x;
    float thr = (*beta_p) * __uint_as_float(rmax[b]);
    size_t base = (size_t)(b * NW + w) * NP;
    if (cmax[b * NCH + (w >> 3)] <= thr) {
        int h = ((4 - (int)(base & 3)) & 3);
        int nv = (NP - h) >> 2;
        int t0 = h + (nv << 2);
        float4* vp = (float4*)(out + base + h);
        float4 z4 = make_float4(0.f, 0.f, 0.f, 0.f);
        for (int v = tid; v < nv; v += 512) vp[v] = z4;
        if (tid < h) out[base + tid] = 0.f;
        if (tid < NP - t0) out[base + t0 + tid] = 0.f;
        return;
    }
    int start = w * STEPW;
    const float* kp = ks + b * NP + start;
    float cut = wcut[b * NW + w];
    const float2* Sb = S + b * NP;
    int k0 = tid, k1 = tid + 512, k2 = tid + 1024, k3 = tid + 1536;
    bool v3 = (k3 < KHALF);
    float2 R0 = tw[k0], R1 = tw[k1], R2 = tw[k2], R3 = tw[k3];
    float Dx0 = kp[19], Dy0 = 0.f, Dx1 = kp[19], Dy1 = 0.f,
          Dx2 = kp[19], Dy2 = 0.f, Dx3 = kp[19], Dy3 = 0.f;
    #pragma unroll
    for (int j = 18; j >= 0; --j) {
        float a = kp[j];
        float nx, ny;
        nx = fmaf(Dx0, R0.x, fmaf(-Dy0, R0.y, a));
        ny = fmaf(Dy0, R0.x, Dx0 * R0.y);
        Dx0 = nx; Dy0 = ny;
        nx = fmaf(Dx1, R1.x, fmaf(-Dy1, R1.y, a));
        ny = fmaf(Dy1, R1.x, Dx1 * R1.y);
        Dx1 = nx; Dy1 = ny;
        nx = fmaf(Dx2, R2.x, fmaf(-Dy2, R2.y, a));
        ny = fmaf(Dy2, R2.x, Dx2 * R2.y);
        Dx2 = nx; Dy2 = ny;
        nx = fmaf(Dx3, R3.x, fmaf(-Dy3, R3.y, a));
        ny = fmaf(Dy3, R3.x, Dx3 * R3.y);
        Dx3 = nx; Dy3 = ny;
    }
    FINBIN(0, k0, true)
    FINBIN(1, k1, true)
    FINBIN(2, k2, true)
    FINBIN(3, k3, v3)
}

extern "C" void kernel_launch(void* const* d_in, const int* in_sizes, int n_in,
                              void* d_out, int out_size, void* d_ws, size_t ws_size,
                              hipStream_t stream) {
    const float* sig       = (const float*)d_in[0];
    const float* alpha_p   = (const float*)d_in[1];
    const float* beta_p    = (const float*)d_in[2];
    const float* gamma_raw = (const float*)d_in[3];
    char* ws = (char*)d_ws;
    float*        ks   = (float*)(ws + 0);
    float2*       tw   = (float2*)(ws + 65536);
    float2*       S    = (float2*)(ws + 98304);
    unsigned int* rmax = (unsigned int*)(ws + 226304);
    float*        cmax = (float*)(ws + 226432);
    float*        wcut = (float*)(ws + 229376);
    float* out = (float*)d_out;

    hipLaunchKernelGGL(dft_init_kernel, dim3(125, BATCH), dim3(512), 0, stream,
                       sig, gamma_raw, ks, tw, S, rmax);
    hipLaunchKernelGGL(window_kernel,   dim3(NCH, BATCH), dim3(512), 0, stream,
                       ks, tw, S, alpha_p, wcut, cmax, rmax);
    hipLaunchKernelGGL(finalize_kernel, dim3(NW, BATCH),  dim3(512), 0, stream,
                       ks, tw, S, wcut, cmax, rmax, beta_p, out);
}